// Round 8
// baseline (387.543 us; speedup 1.0000x reference)
//
#include <hip/hip_runtime.h>
#include <hip/hip_bf16.h>

#define TOK 65536
#define NE  32
#define DD  512
#define HH  1024
#define TPE 2048   // tokens per expert (uniform dispatch)

typedef short s16x8  __attribute__((ext_vector_type(8)));
typedef float f32x16 __attribute__((ext_vector_type(16)));
using u16 = unsigned short;
using u32 = unsigned int;

__device__ __forceinline__ u16 f2bf(float f) {
  __bf16 h = (__bf16)f;
  return __builtin_bit_cast(u16, h);
}
__device__ __forceinline__ u32 pk2(float lo, float hi) {
  return (u32)f2bf(lo) | ((u32)f2bf(hi) << 16);
}
__device__ __forceinline__ int swz(int row, int colb) {
  return (row << 7) + (colb ^ ((row & 7) << 4));
}

#define MFMA(a, b, c) __builtin_amdgcn_mfma_f32_32x32x16_bf16(a, b, c, 0, 0, 0)
#define GLD(src, dst) __builtin_amdgcn_global_load_lds( \
    (const __attribute__((address_space(1))) void*)(src), \
    (__attribute__((address_space(3))) void*)(dst), 16, 0, 0)
#define SETP(n) __builtin_amdgcn_s_setprio(n)
#define SCHEDB() __builtin_amdgcn_sched_barrier(0)
#define SBAR()  __builtin_amdgcn_s_barrier()

// ===========================================================================
// Merged weight prepass (r6-proven): blocks [0,4096) w1,w3 -> w13t
// (bf16 [E][2H][D], 64-row interleave); blocks [4096,8192) w2 -> w2t.
// ===========================================================================
__global__ __launch_bounds__(256) void p23_wt(
    const float* __restrict__ w1, const float* __restrict__ w3,
    const float* __restrict__ w2,
    u16* __restrict__ w13t, u16* __restrict__ w2t) {
  __shared__ __align__(16) u16 L1[64 * 72], L3[64 * 72];
  const int bid0 = blockIdx.x;
  const int t = threadIdx.x;
  const int cg = (t & 15) << 2, rbase = t >> 4;
  const int cb8 = (t & 7) << 3;

  if (bid0 < NE * 128) {              // ---- w1,w3 -> w13t ----
    const int e = bid0 >> 7, rr = bid0 & 127;
    const int d0 = (rr & 7) << 6, h0 = (rr >> 3) << 6;
    const float* const s1 = w1 + (size_t)e * DD * HH + (size_t)d0 * HH + h0;
    const float* const s3 = w3 + (size_t)e * DD * HH + (size_t)d0 * HH + h0;
#pragma unroll
    for (int j = 0; j < 4; ++j) {
      const int dr = rbase + (j << 4);
      const float4 a = *(const float4*)(s1 + (size_t)dr * HH + cg);
      const float4 b = *(const float4*)(s3 + (size_t)dr * HH + cg);
      L1[(cg + 0) * 72 + dr] = f2bf(a.x); L1[(cg + 1) * 72 + dr] = f2bf(a.y);
      L1[(cg + 2) * 72 + dr] = f2bf(a.z); L1[(cg + 3) * 72 + dr] = f2bf(a.w);
      L3[(cg + 0) * 72 + dr] = f2bf(b.x); L3[(cg + 1) * 72 + dr] = f2bf(b.y);
      L3[(cg + 2) * 72 + dr] = f2bf(b.z); L3[(cg + 3) * 72 + dr] = f2bf(b.w);
    }
    __syncthreads();
    u16* const dst = w13t + (size_t)e * (2 * HH) * DD;
#pragma unroll
    for (int j = 0; j < 2; ++j) {
      const int nloc = (t >> 3) + (j << 5);
      const int n = h0 + nloc;
      const int R1 = ((n >> 5) << 6) + (n & 31);
      const uint4 v1 = *(const uint4*)(L1 + nloc * 72 + cb8);
      const uint4 v3 = *(const uint4*)(L3 + nloc * 72 + cb8);
      *(uint4*)(dst + (size_t)R1 * DD + d0 + cb8) = v1;
      *(uint4*)(dst + (size_t)(R1 + 32) * DD + d0 + cb8) = v3;
    }
  } else {                            // ---- w2 -> w2t ----
    const int bid = bid0 - NE * 128;
    const int e = bid >> 7, rr = bid & 127;
    const int d0 = (rr & 7) << 6, h0 = (rr >> 3) << 6;
    const float* const s = w2 + (size_t)e * HH * DD + (size_t)h0 * DD + d0;
#pragma unroll
    for (int j = 0; j < 4; ++j) {
      const int hr = rbase + (j << 4);
      const float4 a = *(const float4*)(s + (size_t)hr * DD + cg);
      L1[(cg + 0) * 72 + hr] = f2bf(a.x); L1[(cg + 1) * 72 + hr] = f2bf(a.y);
      L1[(cg + 2) * 72 + hr] = f2bf(a.z); L1[(cg + 3) * 72 + hr] = f2bf(a.w);
    }
    __syncthreads();
    u16* const dst = w2t + (size_t)e * DD * HH;
#pragma unroll
    for (int j = 0; j < 2; ++j) {
      const int dloc = (t >> 3) + (j << 5);
      const uint4 v = *(const uint4*)(L1 + dloc * 72 + cb8);
      *(uint4*)(dst + (size_t)(d0 + dloc) * HH + h0 + cb8) = v;
    }
  }
}

// ===========================================================================
// g0: 128x128 GEMM, fp32-A reg-staged (inline cvt, no xb prepass),
// B GLD-direct from w13t, XCD chunk swizzle, 3 blocks/CU.
// h = swiglu(x @ w13 + b) -> bf16.
// ===========================================================================
__global__ __launch_bounds__(256, 3) void g0_up(
    const float* __restrict__ x, const u16* __restrict__ Bm,
    const float* __restrict__ bx, const float* __restrict__ by,
    u16* __restrict__ hp) {
  constexpr int K = DD;           // 512
  __shared__ __align__(16) char lds[32768];
  char* const As = lds;
  char* const Bs = lds + 16384;

  int bid = blockIdx.x;
  bid = (bid & 7) * (NE * 256 / 8) + (bid >> 3);   // bijective XCD chunk
  const int e   = bid >> 8;
  const int rr  = bid & 255;
  const int m_t = rr & 15;        // m fastest -> consecutive blocks share B
  const int n_t = rr >> 4;
  const int rowbase = e * TPE + (m_t << 7);

  const int t = threadIdx.x, wv = t >> 6, lane = t & 63;
  const int l31 = lane & 31, half = lane >> 5;
  const int wm = wv >> 1, wn = wv & 1;

  // A staging (fp32 -> bf16, reg path; r1-proven decomposition)
  const int ag  = t & 15;         // col group of 4 fp32
  const int am0 = t >> 4;         // row base 0..15, stride 16
  const float* const xb = x + (size_t)rowbase * K + (ag << 2);
  float4 ra[8];
  auto loadA = [&](int kt) {
    const float* xp = xb + (kt << 6);
#pragma unroll
    for (int j = 0; j < 8; ++j)
      ra[j] = *(const float4*)(xp + (size_t)(am0 + (j << 4)) * K);
  };

  // B staging (GLD, source pre-XORed per rule 21; r2-proven)
  const u16* const Bbase = Bm + ((size_t)e * 2048 + (size_t)n_t * 128) * K;
  int soff[4], lb[4];
#pragma unroll
  for (int j = 0; j < 4; ++j) {
    const int idx = (j << 8) + t;
    const int r = idx >> 3;
    const int cb = ((idx & 7) << 4) ^ ((r & 7) << 4);
    soff[j] = r * K + (cb >> 1);
    lb[j] = ((j << 8) + (wv << 6)) << 4;
  }

  f32x16 c00 = {}, c01 = {}, c10 = {}, c11 = {};
  const int sw  = (l31 & 7) << 4;
  const int ra0 = ((wm << 6) + l31) << 7, ra1 = ra0 + (32 << 7);
  const int rb0 = ((wn << 6) + l31) << 7, rb1 = rb0 + (32 << 7);

  loadA(0);
  for (int kt = 0; kt < 8; ++kt) {
    if (kt) __syncthreads();          // prev readers done; also drains loadA
    // stage A (cvt in-loop, swizzled ds_write)
#pragma unroll
    for (int j = 0; j < 8; ++j) {
      const int m = am0 + (j << 4);
      uint2 v; v.x = pk2(ra[j].x, ra[j].y); v.y = pk2(ra[j].z, ra[j].w);
      *(uint2*)(As + swz(m, ag << 3)) = v;
    }
    // stage B (DMA)
    const u16* const Bk = Bbase + (kt << 6);
#pragma unroll
    for (int j = 0; j < 4; ++j) GLD(Bk + soff[j], Bs + lb[j]);
    __syncthreads();                  // drains ds_write lgkm + B vmcnt
    if (kt < 7) loadA(kt + 1);        // HBM latency hides under MFMA
#pragma unroll
    for (int ks = 0; ks < 4; ++ks) {
      const int ko = ((ks << 5) + (half << 4)) ^ sw;
      const s16x8 a0 = *(const s16x8*)(As + ra0 + ko);
      const s16x8 a1 = *(const s16x8*)(As + ra1 + ko);
      const s16x8 b0 = *(const s16x8*)(Bs + rb0 + ko);
      const s16x8 b1 = *(const s16x8*)(Bs + rb1 + ko);
      c00 = MFMA(a0, b0, c00); c01 = MFMA(a0, b1, c01);
      c10 = MFMA(a1, b0, c10); c11 = MFMA(a1, b1, c11);
    }
  }

  const int hcol = (n_t << 6) + (wn << 5) + l31;
  const float bv1 = bx[e * HH + hcol];
  const float bv3 = by[e * HH + hcol];
#pragma unroll
  for (int mf = 0; mf < 2; ++mf) {
    const f32x16 A1 = mf ? c10 : c00;
    const f32x16 A3 = mf ? c11 : c01;
#pragma unroll
    for (int rg = 0; rg < 16; ++rg) {
      // C/D map: col=lane&31, row=(rg&3)+8*(rg>>2)+4*(lane>>5)
      const int grow = rowbase + (wm << 6) + (mf << 5) +
                       (rg & 3) + ((rg >> 2) << 3) + (half << 2);
      const float s1 = A1[rg] + bv1;
      const float s3 = A3[rg] + bv3;
      hp[(size_t)grow * HH + hcol] = f2bf(s1 * s3 / (1.0f + __expf(-s1)));
    }
  }
}

// ===========================================================================
// g1: r5/r7-proven 256x256 4-phase pipelined GEMM (reads-pre-barrier), K=1024.
// A=h bf16 [T,1024], B=w2t panels, epilogue +b2 -> out fp32.
// ===========================================================================
__global__ __launch_bounds__(512, 2) void g1_down(
    const u16* __restrict__ A, const u16* __restrict__ Bm,
    const float* __restrict__ bx, float* __restrict__ op) {
  constexpr int K  = HH;                // 1024
  constexpr int NT = K >> 6;            // 16
  constexpr int NB = 2;                 // 256-wide n-tiles per expert
  constexpr int NWG = NE * 8 * NB;      // 512
  __shared__ __align__(16) char lds[131072];

  int bid = blockIdx.x;
  bid = (bid & 7) * (NWG / 8) + (bid >> 3);
  const int e   = bid / (8 * NB);
  const int rr  = bid % (8 * NB);
  const int m_t = rr & 7;
  const int n_t = rr >> 3;
  const int rowbase = e * TPE + (m_t << 8);

  const int t = threadIdx.x;
  const int wv = t >> 6, lane = t & 63;
  const int l31 = lane & 31, half = lane >> 5;
  const int wm = wv >> 2, wn = wv & 3;  // 2 x 4 waves; wave owns 128x64

  const u16* const Abase = A + (size_t)rowbase * K;
  const u16* const Bbase = Bm + ((size_t)e * NB + n_t) * 256 * K;

  int srcoff0, srcoff1;
  {
    const int c0 = t,       lr0 = c0 >> 3, s0 = (c0 & 7) ^ (lr0 & 7);
    const int c1 = 512 + t, lr1 = c1 >> 3, s1 = (c1 & 7) ^ (lr1 & 7);
    srcoff0 = ((lr0 << 1) | (s0 >> 2)) * K + ((s0 & 3) << 3);
    srcoff1 = ((lr1 << 1) | (s1 >> 2)) * K + ((s1 & 3) << 3);
  }
  const int t16 = t << 4;

  auto stageQ = [&](int tau, int q) {   // q: 0=Ak0 1=Bk0 2=Ak1 3=Bk1
    const u16* const src = ((q & 1) ? Bbase : Abase) + tau * 64 + (q >> 1) * 32;
    char* const dst = lds + ((tau & 1) << 16) + (q << 14);
    GLD(src + srcoff0, dst + t16);
    GLD(src + srcoff1, dst + 8192 + t16);
  };

  const int lrow_off = l31 >> 1;
  const int pbit = l31 & 1;
  const int sw7 = lrow_off & 7;
  const int sA0 = (((pbit << 2) | 0 | half) ^ sw7) << 4;  // ksp=0
  const int sA1 = (((pbit << 2) | 2 | half) ^ sw7) << 4;  // ksp=1
  const int aoff = ((wm << 6) + lrow_off) << 7;
  const int boff = ((wn << 5) + lrow_off) << 7;

  f32x16 acc[4][2] = {};
  s16x8 b00{}, b01{}, b10{}, b11{};

#define VM4 asm volatile("s_waitcnt vmcnt(4)" ::: "memory")
#define VM0 asm volatile("s_waitcnt vmcnt(0)" ::: "memory")
#define LGKM0 asm volatile("s_waitcnt lgkmcnt(0)" ::: "memory")
#define NOPV ((void)0)

#define PHASE(CB, KH, MH, DOB, STG, VM) do { \
  const char* const Aq = (CB) + ((KH) << 15); \
  const char* const Bq = Aq + 16384; \
  if (DOB) { \
    b00 = *(const s16x8*)(Bq + boff + 0 * 2048 + sA0); \
    b01 = *(const s16x8*)(Bq + boff + 1 * 2048 + sA0); \
    b10 = *(const s16x8*)(Bq + boff + 0 * 2048 + sA1); \
    b11 = *(const s16x8*)(Bq + boff + 1 * 2048 + sA1); \
  } \
  const s16x8 a0 = *(const s16x8*)(Aq + aoff + (2 * (MH)) * 2048 + sA0); \
  const s16x8 a1 = *(const s16x8*)(Aq + aoff + (2 * (MH)) * 2048 + sA1); \
  const s16x8 a2 = *(const s16x8*)(Aq + aoff + (2 * (MH) + 1) * 2048 + sA0); \
  const s16x8 a3 = *(const s16x8*)(Aq + aoff + (2 * (MH) + 1) * 2048 + sA1); \
  STG; VM; \
  SCHEDB(); SBAR(); LGKM0; SCHEDB(); \
  SETP(1); \
  acc[2 * (MH)][0]     = MFMA(a0, b00, acc[2 * (MH)][0]); \
  acc[2 * (MH)][1]     = MFMA(a0, b01, acc[2 * (MH)][1]); \
  acc[2 * (MH)][0]     = MFMA(a1, b10, acc[2 * (MH)][0]); \
  acc[2 * (MH)][1]     = MFMA(a1, b11, acc[2 * (MH)][1]); \
  acc[2 * (MH) + 1][0] = MFMA(a2, b00, acc[2 * (MH) + 1][0]); \
  acc[2 * (MH) + 1][1] = MFMA(a2, b01, acc[2 * (MH) + 1][1]); \
  acc[2 * (MH) + 1][0] = MFMA(a3, b10, acc[2 * (MH) + 1][0]); \
  acc[2 * (MH) + 1][1] = MFMA(a3, b11, acc[2 * (MH) + 1][1]); \
  SETP(0); \
} while (0)

  stageQ(0, 0); stageQ(0, 1); stageQ(0, 2); stageQ(0, 3);
  VM4; SCHEDB(); SBAR();

  for (int kt = 0; kt < NT - 1; ++kt) {
    const char* const cb = lds + ((kt & 1) << 16);
    PHASE(cb, 0, 0, true,  (stageQ(kt + 1, 0), stageQ(kt + 1, 1)), NOPV);
    PHASE(cb, 0, 1, false, NOPV, VM4);
    PHASE(cb, 1, 0, true,  (stageQ(kt + 1, 2), stageQ(kt + 1, 3)), NOPV);
    PHASE(cb, 1, 1, false, NOPV, VM4);
  }
  {
    const char* const cb = lds + (((NT - 1) & 1) << 16);
    PHASE(cb, 0, 0, true,  NOPV, NOPV);
    PHASE(cb, 0, 1, false, NOPV, VM0);
    PHASE(cb, 1, 0, true,  NOPV, NOPV);
    PHASE(cb, 1, 1, false, NOPV, NOPV);
  }

#undef PHASE
#undef VM4
#undef VM0
#undef LGKM0
#undef NOPV

#pragma unroll
  for (int mf = 0; mf < 4; ++mf) {
#pragma unroll
    for (int nf = 0; nf < 2; ++nf) {
      const int col = (n_t << 8) + (wn << 6) + (nf << 5) + l31;
      const float bv = bx[e * DD + col];
#pragma unroll
      for (int rg = 0; rg < 16; ++rg) {
        const int grow = rowbase + (wm << 7) + (mf << 5) +
                         (rg & 3) + ((rg >> 2) << 3) + (half << 2);
        op[(size_t)grow * DD + col] = acc[mf][nf][rg] + bv;
      }
    }
  }
}

// ===========================================================================
// FALLBACK (round-1 reg-staged path, used only if ws is too small)
// ===========================================================================
__global__ __launch_bounds__(256, 2) void k1_up_swiglu(
    const float* __restrict__ x,  const float* __restrict__ w1,
    const float* __restrict__ b1, const float* __restrict__ w3,
    const float* __restrict__ b3, u16* __restrict__ hbuf) {
  __shared__ __align__(16) char lds[32768];
  char* const As  = lds;
  char* const B1s = lds + 16384;
  char* const B3s = lds + 24576;
  const int bid = blockIdx.x;
  const int e = bid >> 8, rr = bid & 255;
  const int m_t = rr & 15, n_t = rr >> 4;
  const int rowbase = e * TPE + (m_t << 7), colbase = n_t << 6;
  const int t = threadIdx.x, wv = t >> 6, lane = t & 63;
  const int l31 = lane & 31, half = lane >> 5;
  const int wm = wv >> 1, wn = wv & 1;
  const int ag = t & 15, am0 = t >> 4, bn = t & 63, bk0 = t >> 6;
  const float* const xb = x + (size_t)rowbase * DD + (ag << 2);
  const size_t woff = (size_t)e * (DD * HH) + colbase + bn;
  const float* const w1b = w1 + woff;
  const float* const w3b = w3 + woff;
  float4 ra[8]; float rb1[16], rb3[16];
  auto gload = [&](int kt) {
    const float* xp = xb + (kt << 6);
#pragma unroll
    for (int j = 0; j < 8; ++j)
      ra[j] = *(const float4*)(xp + (size_t)(am0 + (j << 4)) * DD);
#pragma unroll
    for (int j = 0; j < 2; ++j) {
      const int k0 = (kt << 6) + ((bk0 + (j << 2)) << 3);
#pragma unroll
      for (int i = 0; i < 8; ++i) {
        rb1[(j << 3) + i] = w1b[(size_t)(k0 + i) * HH];
        rb3[(j << 3) + i] = w3b[(size_t)(k0 + i) * HH];
      }
    }
  };
  f32x16 acc10 = {}, acc11 = {}, acc30 = {}, acc31 = {};
  gload(0);
  for (int kt = 0; kt < 8; ++kt) {
    if (kt) __syncthreads();
#pragma unroll
    for (int j = 0; j < 8; ++j) {
      const int m = am0 + (j << 4);
      uint2 v; v.x = pk2(ra[j].x, ra[j].y); v.y = pk2(ra[j].z, ra[j].w);
      *(uint2*)(As + swz(m, ag << 3)) = v;
    }
#pragma unroll
    for (int j = 0; j < 2; ++j) {
      const int kg = bk0 + (j << 2);
      uint4 v;
      v.x = pk2(rb1[(j << 3) + 0], rb1[(j << 3) + 1]);
      v.y = pk2(rb1[(j << 3) + 2], rb1[(j << 3) + 3]);
      v.z = pk2(rb1[(j << 3) + 4], rb1[(j << 3) + 5]);
      v.w = pk2(rb1[(j << 3) + 6], rb1[(j << 3) + 7]);
      *(uint4*)(B1s + swz(bn, kg << 4)) = v;
      v.x = pk2(rb3[(j << 3) + 0], rb3[(j << 3) + 1]);
      v.y = pk2(rb3[(j << 3) + 2], rb3[(j << 3) + 3]);
      v.z = pk2(rb3[(j << 3) + 4], rb3[(j << 3) + 5]);
      v.w = pk2(rb3[(j << 3) + 6], rb3[(j << 3) + 7]);
      *(uint4*)(B3s + swz(bn, kg << 4)) = v;
    }
    __syncthreads();
    if (kt < 7) gload(kt + 1);
#pragma unroll
    for (int kk = 0; kk < 4; ++kk) {
      const int colb = (kk << 5) + (half << 4);
      const s16x8 a0 = *(const s16x8*)(As  + swz((wm << 6) + l31,      colb));
      const s16x8 a1 = *(const s16x8*)(As  + swz((wm << 6) + 32 + l31, colb));
      const s16x8 f1 = *(const s16x8*)(B1s + swz((wn << 5) + l31,      colb));
      const s16x8 f3 = *(const s16x8*)(B3s + swz((wn << 5) + l31,      colb));
      acc10 = MFMA(a0, f1, acc10); acc30 = MFMA(a0, f3, acc30);
      acc11 = MFMA(a1, f1, acc11); acc31 = MFMA(a1, f3, acc31);
    }
  }
  const int gcol = colbase + (wn << 5) + l31;
  const float bv1 = b1[e * HH + gcol], bv3 = b3[e * HH + gcol];
  u16* const hp = hbuf + gcol;
#pragma unroll
  for (int mb = 0; mb < 2; ++mb) {
    const f32x16 A1 = mb ? acc11 : acc10;
    const f32x16 A3 = mb ? acc31 : acc30;
#pragma unroll
    for (int rg = 0; rg < 16; ++rg) {
      const int grow = rowbase + (wm << 6) + (mb << 5) +
                       (rg & 3) + ((rg >> 2) << 3) + (half << 2);
      const float s1 = A1[rg] + bv1, s3 = A3[rg] + bv3;
      hp[(size_t)grow * HH] = f2bf(s1 * s3 / (1.0f + __expf(-s1)));
    }
  }
}

__global__ __launch_bounds__(256, 2) void k2_down(
    const u16* __restrict__ hbuf, const float* __restrict__ w2,
    const float* __restrict__ b2, float* __restrict__ out) {
  __shared__ __align__(16) char lds[32768];
  char* const As = lds;
  char* const Bs = lds + 16384;
  const int bid = blockIdx.x;
  const int e = bid >> 6, rr = bid & 63;
  const int m_t = rr & 15, n_t = rr >> 4;
  const int rowbase = e * TPE + (m_t << 7), colbase = n_t << 7;
  const int t = threadIdx.x, wv = t >> 6, lane = t & 63;
  const int l31 = lane & 31, half = lane >> 5;
  const int wm = wv >> 1, wn = wv & 1;
  const int ag = t & 7, am0 = t >> 3, bnn = t & 127, bk0 = t >> 7;
  const u16* const hb = hbuf + (size_t)rowbase * HH + (ag << 3);
  const float* const w2b = w2 + (size_t)e * (HH * DD) + colbase + bnn;
  uint4 ra[4]; float rb[32];
  auto gload = [&](int kt) {
#pragma unroll
    for (int j = 0; j < 4; ++j)
      ra[j] = *(const uint4*)(hb + (size_t)(am0 + (j << 5)) * HH + (kt << 6));
#pragma unroll
    for (int j = 0; j < 4; ++j) {
      const int k0 = (kt << 6) + ((bk0 + (j << 1)) << 3);
#pragma unroll
      for (int i = 0; i < 8; ++i)
        rb[(j << 3) + i] = w2b[(size_t)(k0 + i) * DD];
    }
  };
  f32x16 c00 = {}, c01 = {}, c10 = {}, c11 = {};
  gload(0);
  for (int kt = 0; kt < 16; ++kt) {
    if (kt) __syncthreads();
#pragma unroll
    for (int j = 0; j < 4; ++j)
      *(uint4*)(As + swz(am0 + (j << 5), ag << 4)) = ra[j];
#pragma unroll
    for (int j = 0; j < 4; ++j) {
      const int kg = bk0 + (j << 1);
      uint4 v;
      v.x = pk2(rb[(j << 3) + 0], rb[(j << 3) + 1]);
      v.y = pk2(rb[(j << 3) + 2], rb[(j << 3) + 3]);
      v.z = pk2(rb[(j << 3) + 4], rb[(j << 3) + 5]);
      v.w = pk2(rb[(j << 3) + 6], rb[(j << 3) + 7]);
      *(uint4*)(Bs + swz(bnn, kg << 4)) = v;
    }
    __syncthreads();
    if (kt < 15) gload(kt + 1);
#pragma unroll
    for (int kk = 0; kk < 4; ++kk) {
      const int colb = (kk << 5) + (half << 4);
      const s16x8 af0 = *(const s16x8*)(As + swz((wm << 6) + l31,      colb));
      const s16x8 af1 = *(const s16x8*)(As + swz((wm << 6) + 32 + l31, colb));
      const s16x8 bf0 = *(const s16x8*)(Bs + swz((wn << 6) + l31,      colb));
      const s16x8 bf1 = *(const s16x8*)(Bs + swz((wn << 6) + 32 + l31, colb));
      c00 = MFMA(af0, bf0, c00); c01 = MFMA(af0, bf1, c01);
      c10 = MFMA(af1, bf0, c10); c11 = MFMA(af1, bf1, c11);
    }
  }
#pragma unroll
  for (int mb = 0; mb < 2; ++mb) {
#pragma unroll
    for (int nb = 0; nb < 2; ++nb) {
      const f32x16 c = mb ? (nb ? c11 : c10) : (nb ? c01 : c00);
      const int gcol = colbase + (wn << 6) + (nb << 5) + l31;
      const float bv = b2[e * DD + gcol];
#pragma unroll
      for (int rg = 0; rg < 16; ++rg) {
        const int grow = rowbase + (wm << 6) + (mb << 5) +
                         (rg & 3) + ((rg >> 2) << 3) + (half << 2);
        out[(size_t)grow * DD + gcol] = c[rg] + bv;
      }
    }
  }
}

// ---------------------------------------------------------------------------
extern "C" void kernel_launch(void* const* d_in, const int* in_sizes, int n_in,
                              void* d_out, int out_size, void* d_ws, size_t ws_size,
                              hipStream_t stream) {
  const float* x  = (const float*)d_in[0];
  const float* w1 = (const float*)d_in[1];
  const float* b1 = (const float*)d_in[2];
  const float* w3 = (const float*)d_in[3];
  const float* b3 = (const float*)d_in[4];
  const float* w2 = (const float*)d_in[5];
  const float* b2 = (const float*)d_in[6];

  const size_t W13T_B = (size_t)NE * 2 * HH * DD * 2;  //  64 MiB
  const size_t W2T_B  = (size_t)NE * DD * HH * 2;      //  32 MiB
  const size_t H_B    = (size_t)TOK * HH * 2;          // 128 MiB

  if (ws_size >= W13T_B + W2T_B + H_B) {
    u16* const w13t = (u16*)d_ws;
    u16* const w2t  = (u16*)((char*)d_ws + W13T_B);
    u16* const hbuf = (u16*)((char*)d_ws + W13T_B + W2T_B);

    p23_wt <<<dim3(NE * 256), dim3(256), 0, stream>>>(w1, w3, w2, w13t, w2t);
    g0_up  <<<dim3(NE * 256), dim3(256), 0, stream>>>(x, w13t, b1, b3, hbuf);
    g1_down<<<dim3(NE * 16),  dim3(512), 0, stream>>>(hbuf, w2t, b2, (float*)d_out);
  } else {
    u16* hbuf = (ws_size >= H_B) ? (u16*)d_ws : (u16*)d_out;
    k1_up_swiglu<<<dim3(NE * 256), dim3(256), 0, stream>>>(x, w1, b1, w3, b3, hbuf);
    k2_down<<<dim3(NE * 64), dim3(256), 0, stream>>>(hbuf, w2, b2, (float*)d_out);
  }
}

// Round 9
// 360.857 us; speedup vs baseline: 1.0740x; 1.0740x over previous
//
#include <hip/hip_runtime.h>
#include <hip/hip_bf16.h>

#define TOK 65536
#define NE  32
#define DD  512
#define HH  1024
#define TPE 2048   // tokens per expert (uniform dispatch)

typedef short s16x8  __attribute__((ext_vector_type(8)));
typedef float f32x16 __attribute__((ext_vector_type(16)));
using u16 = unsigned short;
using u32 = unsigned int;

__device__ __forceinline__ u16 f2bf(float f) {
  __bf16 h = (__bf16)f;
  return __builtin_bit_cast(u16, h);
}
__device__ __forceinline__ u32 pk2(float lo, float hi) {
  return (u32)f2bf(lo) | ((u32)f2bf(hi) << 16);
}
__device__ __forceinline__ int swz(int row, int colb) {
  return (row << 7) + (colb ^ ((row & 7) << 4));
}

#define MFMA(a, b, c) __builtin_amdgcn_mfma_f32_32x32x16_bf16(a, b, c, 0, 0, 0)
#define GLD(src, dst) __builtin_amdgcn_global_load_lds( \
    (const __attribute__((address_space(1))) void*)(src), \
    (__attribute__((address_space(3))) void*)(dst), 16, 0, 0)
#define SETP(n) __builtin_amdgcn_s_setprio(n)
#define SCHEDB() __builtin_amdgcn_sched_barrier(0)
#define SBAR()  __builtin_amdgcn_s_barrier()

// ===========================================================================
// Merged prepass: blocks [0,16384) x->bf16; [16384,20480) w1,w3 -> w13t
// (bf16 [E][2H][D], 64-row interleave); [20480,24576) w2 -> w2t.
// All three ranges are pure-BW transforms (r2/r6-proven bodies).
// ===========================================================================
__global__ __launch_bounds__(256) void p123(
    const float* __restrict__ x,  const float* __restrict__ w1,
    const float* __restrict__ w3, const float* __restrict__ w2,
    u16* __restrict__ xb, u16* __restrict__ w13t, u16* __restrict__ w2t) {
  __shared__ __align__(16) u16 L1[64 * 72], L3[64 * 72];
  const int bid0 = blockIdx.x;
  const int t = threadIdx.x;

  if (bid0 < 16384) {                 // ---- x -> xb ----
    const size_t i = ((size_t)bid0 * 256 + t) * 8;
    const float4 a = *(const float4*)(x + i);
    const float4 b = *(const float4*)(x + i + 4);
    uint4 v;
    v.x = pk2(a.x, a.y); v.y = pk2(a.z, a.w);
    v.z = pk2(b.x, b.y); v.w = pk2(b.z, b.w);
    *(uint4*)(xb + i) = v;
    return;
  }
  const int cg = (t & 15) << 2, rbase = t >> 4;
  const int cb8 = (t & 7) << 3;
  if (bid0 < 16384 + NE * 128) {      // ---- w1,w3 -> w13t ----
    const int bid = bid0 - 16384;
    const int e = bid >> 7, rr = bid & 127;
    const int d0 = (rr & 7) << 6, h0 = (rr >> 3) << 6;
    const float* const s1 = w1 + (size_t)e * DD * HH + (size_t)d0 * HH + h0;
    const float* const s3 = w3 + (size_t)e * DD * HH + (size_t)d0 * HH + h0;
#pragma unroll
    for (int j = 0; j < 4; ++j) {
      const int dr = rbase + (j << 4);
      const float4 a = *(const float4*)(s1 + (size_t)dr * HH + cg);
      const float4 b = *(const float4*)(s3 + (size_t)dr * HH + cg);
      L1[(cg + 0) * 72 + dr] = f2bf(a.x); L1[(cg + 1) * 72 + dr] = f2bf(a.y);
      L1[(cg + 2) * 72 + dr] = f2bf(a.z); L1[(cg + 3) * 72 + dr] = f2bf(a.w);
      L3[(cg + 0) * 72 + dr] = f2bf(b.x); L3[(cg + 1) * 72 + dr] = f2bf(b.y);
      L3[(cg + 2) * 72 + dr] = f2bf(b.z); L3[(cg + 3) * 72 + dr] = f2bf(b.w);
    }
    __syncthreads();
    u16* const dst = w13t + (size_t)e * (2 * HH) * DD;
#pragma unroll
    for (int j = 0; j < 2; ++j) {
      const int nloc = (t >> 3) + (j << 5);
      const int n = h0 + nloc;
      const int R1 = ((n >> 5) << 6) + (n & 31);
      const uint4 v1 = *(const uint4*)(L1 + nloc * 72 + cb8);
      const uint4 v3 = *(const uint4*)(L3 + nloc * 72 + cb8);
      *(uint4*)(dst + (size_t)R1 * DD + d0 + cb8) = v1;
      *(uint4*)(dst + (size_t)(R1 + 32) * DD + d0 + cb8) = v3;
    }
  } else {                            // ---- w2 -> w2t ----
    const int bid = bid0 - 16384 - NE * 128;
    const int e = bid >> 7, rr = bid & 127;
    const int d0 = (rr & 7) << 6, h0 = (rr >> 3) << 6;
    const float* const s = w2 + (size_t)e * HH * DD + (size_t)h0 * DD + d0;
#pragma unroll
    for (int j = 0; j < 4; ++j) {
      const int hr = rbase + (j << 4);
      const float4 a = *(const float4*)(s + (size_t)hr * DD + cg);
      L1[(cg + 0) * 72 + hr] = f2bf(a.x); L1[(cg + 1) * 72 + hr] = f2bf(a.y);
      L1[(cg + 2) * 72 + hr] = f2bf(a.z); L1[(cg + 3) * 72 + hr] = f2bf(a.w);
    }
    __syncthreads();
    u16* const dst = w2t + (size_t)e * DD * HH;
#pragma unroll
    for (int j = 0; j < 2; ++j) {
      const int dloc = (t >> 3) + (j << 5);
      const uint4 v = *(const uint4*)(L1 + dloc * 72 + cb8);
      *(uint4*)(dst + (size_t)(d0 + dloc) * HH + h0 + cb8) = v;
    }
  }
}

// ===========================================================================
// g0_pers: PERSISTENT 4-phase up-proj. 256 blocks (e x n_t), 1/CU, 8 waves.
// Each block sweeps 8 m-tiles x 8 K-tiles as one 64-step pipeline
// (vt = mi*8+kt); staging of vt+1 crosses m-boundaries; epilogue per m-tile.
// A = xb bf16 [T,512]; B = w13t 256-row interleaved panels.
// h = swiglu(x@w13 + b) -> bf16.
// ===========================================================================
__global__ __launch_bounds__(512, 2) void g0_pers(
    const u16* __restrict__ A, const u16* __restrict__ Bm,
    const float* __restrict__ bx, const float* __restrict__ by,
    u16* __restrict__ hp) {
  constexpr int K   = DD;              // 512
  constexpr int NVT = 64;              // 8 m-tiles * 8 K-tiles
  __shared__ __align__(16) char lds[131072];

  int bid = blockIdx.x;
  bid = (bid & 7) * 32 + (bid >> 3);   // 256 blocks -> 8 XCD chunks of 32
  const int e   = bid >> 3;
  const int n_t = bid & 7;

  const int t = threadIdx.x;
  const int wv = t >> 6, lane = t & 63;
  const int l31 = lane & 31, half = lane >> 5;
  const int wm = wv >> 2, wn = wv & 3;  // 2 x 4 waves; wave owns 128x64

  const u16* const Abase = A + (size_t)e * TPE * K;
  const u16* const Bbase = Bm + ((size_t)e * 8 + n_t) * 256 * K;

  // staging precompute (r5-verified inverse swizzle, K=512)
  int srcoff0, srcoff1;
  {
    const int c0 = t,       lr0 = c0 >> 3, s0 = (c0 & 7) ^ (lr0 & 7);
    const int c1 = 512 + t, lr1 = c1 >> 3, s1 = (c1 & 7) ^ (lr1 & 7);
    srcoff0 = ((lr0 << 1) | (s0 >> 2)) * K + ((s0 & 3) << 3);
    srcoff1 = ((lr1 << 1) | (s1 >> 2)) * K + ((s1 & 3) << 3);
  }
  const int t16 = t << 4;

  auto stageQ = [&](int vt1, int q) {   // q: 0=Ak0 1=Bk0 2=Ak1 3=Bk1
    const int mi = vt1 >> 3, kt = vt1 & 7;
    const u16* const src =
        ((q & 1) ? Bbase : (Abase + ((size_t)mi << 8) * K)) +
        kt * 64 + (q >> 1) * 32;
    char* const dst = lds + ((vt1 & 1) << 16) + (q << 14);
    GLD(src + srcoff0, dst + t16);
    GLD(src + srcoff1, dst + 8192 + t16);
  };

  // fragment-read precompute (r5-verified)
  const int lrow_off = l31 >> 1;
  const int pbit = l31 & 1;
  const int sw7 = lrow_off & 7;
  const int sA0 = (((pbit << 2) | 0 | half) ^ sw7) << 4;  // ksp=0
  const int sA1 = (((pbit << 2) | 2 | half) ^ sw7) << 4;  // ksp=1
  const int aoff = ((wm << 6) + lrow_off) << 7;
  const int boff = ((wn << 5) + lrow_off) << 7;

  // hoisted bias loads (issued BEFORE prologue stage; see vmcnt ledger)
  const int g = (n_t << 2) + wn;        // w13t interleave group
  const int hcol = (g << 5) + l31;
  const float bv1 = bx[e * HH + hcol];
  const float bv3 = by[e * HH + hcol];

  f32x16 acc[4][2] = {};
  s16x8 b00{}, b01{}, b10{}, b11{};

#define VM4 asm volatile("s_waitcnt vmcnt(4)" ::: "memory")
#define VM0 asm volatile("s_waitcnt vmcnt(0)" ::: "memory")
#define NOPV ((void)0)

#define PHASE(CB, KH, MH, DOB, STG, VM) do { \
  const char* const Aq = (CB) + ((KH) << 15); \
  const char* const Bq = Aq + 16384; \
  if (DOB) { \
    b00 = *(const s16x8*)(Bq + boff + 0 * 2048 + sA0); \
    b01 = *(const s16x8*)(Bq + boff + 1 * 2048 + sA0); \
    b10 = *(const s16x8*)(Bq + boff + 0 * 2048 + sA1); \
    b11 = *(const s16x8*)(Bq + boff + 1 * 2048 + sA1); \
  } \
  const s16x8 a0 = *(const s16x8*)(Aq + aoff + (2 * (MH)) * 2048 + sA0); \
  const s16x8 a1 = *(const s16x8*)(Aq + aoff + (2 * (MH)) * 2048 + sA1); \
  const s16x8 a2 = *(const s16x8*)(Aq + aoff + (2 * (MH) + 1) * 2048 + sA0); \
  const s16x8 a3 = *(const s16x8*)(Aq + aoff + (2 * (MH) + 1) * 2048 + sA1); \
  STG; VM; \
  SCHEDB(); SBAR(); \
  asm volatile("s_waitcnt lgkmcnt(0)" ::: "memory"); \
  SCHEDB(); \
  SETP(1); \
  acc[2 * (MH)][0]     = MFMA(a0, b00, acc[2 * (MH)][0]); \
  acc[2 * (MH)][1]     = MFMA(a0, b01, acc[2 * (MH)][1]); \
  acc[2 * (MH)][0]     = MFMA(a1, b10, acc[2 * (MH)][0]); \
  acc[2 * (MH)][1]     = MFMA(a1, b11, acc[2 * (MH)][1]); \
  acc[2 * (MH) + 1][0] = MFMA(a2, b00, acc[2 * (MH) + 1][0]); \
  acc[2 * (MH) + 1][1] = MFMA(a2, b01, acc[2 * (MH) + 1][1]); \
  acc[2 * (MH) + 1][0] = MFMA(a3, b10, acc[2 * (MH) + 1][0]); \
  acc[2 * (MH) + 1][1] = MFMA(a3, b11, acc[2 * (MH) + 1][1]); \
  SETP(0); \
} while (0)

  // epilogue for m-tile mi: bias + SwiGLU, write h, reset acc
  auto epilogue = [&](int mi) {
    const int rowbase = e * TPE + (mi << 8);
#pragma unroll
    for (int mf = 0; mf < 4; ++mf) {
#pragma unroll
      for (int rg = 0; rg < 16; ++rg) {
        // C/D map: col=lane&31, row=(rg&3)+8*(rg>>2)+4*(lane>>5)
        const int grow = rowbase + (wm << 7) + (mf << 5) +
                         (rg & 3) + ((rg >> 2) << 3) + (half << 2);
        const float s1 = acc[mf][0][rg] + bv1;
        const float s3 = acc[mf][1][rg] + bv3;
        hp[(size_t)grow * HH + hcol] = f2bf(s1 * s3 / (1.0f + __expf(-s1)));
      }
    }
#pragma unroll
    for (int mf = 0; mf < 4; ++mf) {
      acc[mf][0] = (f32x16){};
      acc[mf][1] = (f32x16){};
    }
  };

  // prologue: 2 bias loads + 8 stage loads outstanding; vmcnt(4) -> 6 oldest
  // (bias x2 + kh0 quarters x4) landed.
  stageQ(0, 0); stageQ(0, 1); stageQ(0, 2); stageQ(0, 3);
  VM4; SCHEDB(); SBAR();

  for (int vt = 0; vt < NVT - 1; ++vt) {
    const char* const cb = lds + ((vt & 1) << 16);
    PHASE(cb, 0, 0, true,  (stageQ(vt + 1, 0), stageQ(vt + 1, 1)), NOPV);
    PHASE(cb, 0, 1, false, NOPV, VM4);
    PHASE(cb, 1, 0, true,  (stageQ(vt + 1, 2), stageQ(vt + 1, 3)), NOPV);
    PHASE(cb, 1, 1, false, NOPV, VM4);
    if ((vt & 7) == 7) epilogue(vt >> 3);
  }
  { // peeled vt = 63
    const char* const cb = lds + (((NVT - 1) & 1) << 16);
    PHASE(cb, 0, 0, true,  NOPV, NOPV);
    PHASE(cb, 0, 1, false, NOPV, VM0);
    PHASE(cb, 1, 0, true,  NOPV, NOPV);
    PHASE(cb, 1, 1, false, NOPV, NOPV);
  }
  epilogue(7);

#undef PHASE
#undef VM4
#undef VM0
#undef NOPV
}

// ===========================================================================
// g1: r5/r7-proven 256x256 4-phase pipelined GEMM (reads-pre-barrier), K=1024.
// A=h bf16 [T,1024], B=w2t panels, epilogue +b2 -> out fp32.
// ===========================================================================
__global__ __launch_bounds__(512, 2) void g1_down(
    const u16* __restrict__ A, const u16* __restrict__ Bm,
    const float* __restrict__ bx, float* __restrict__ op) {
  constexpr int K  = HH;                // 1024
  constexpr int NT = K >> 6;            // 16
  constexpr int NB = 2;                 // 256-wide n-tiles per expert
  constexpr int NWG = NE * 8 * NB;      // 512
  __shared__ __align__(16) char lds[131072];

  int bid = blockIdx.x;
  bid = (bid & 7) * (NWG / 8) + (bid >> 3);
  const int e   = bid / (8 * NB);
  const int rr  = bid % (8 * NB);
  const int m_t = rr & 7;
  const int n_t = rr >> 3;
  const int rowbase = e * TPE + (m_t << 8);

  const int t = threadIdx.x;
  const int wv = t >> 6, lane = t & 63;
  const int l31 = lane & 31, half = lane >> 5;
  const int wm = wv >> 2, wn = wv & 3;  // 2 x 4 waves; wave owns 128x64

  const u16* const Abase = A + (size_t)rowbase * K;
  const u16* const Bbase = Bm + ((size_t)e * NB + n_t) * 256 * K;

  int srcoff0, srcoff1;
  {
    const int c0 = t,       lr0 = c0 >> 3, s0 = (c0 & 7) ^ (lr0 & 7);
    const int c1 = 512 + t, lr1 = c1 >> 3, s1 = (c1 & 7) ^ (lr1 & 7);
    srcoff0 = ((lr0 << 1) | (s0 >> 2)) * K + ((s0 & 3) << 3);
    srcoff1 = ((lr1 << 1) | (s1 >> 2)) * K + ((s1 & 3) << 3);
  }
  const int t16 = t << 4;

  auto stageQ = [&](int tau, int q) {   // q: 0=Ak0 1=Bk0 2=Ak1 3=Bk1
    const u16* const src = ((q & 1) ? Bbase : Abase) + tau * 64 + (q >> 1) * 32;
    char* const dst = lds + ((tau & 1) << 16) + (q << 14);
    GLD(src + srcoff0, dst + t16);
    GLD(src + srcoff1, dst + 8192 + t16);
  };

  const int lrow_off = l31 >> 1;
  const int pbit = l31 & 1;
  const int sw7 = lrow_off & 7;
  const int sA0 = (((pbit << 2) | 0 | half) ^ sw7) << 4;  // ksp=0
  const int sA1 = (((pbit << 2) | 2 | half) ^ sw7) << 4;  // ksp=1
  const int aoff = ((wm << 6) + lrow_off) << 7;
  const int boff = ((wn << 5) + lrow_off) << 7;

  f32x16 acc[4][2] = {};
  s16x8 b00{}, b01{}, b10{}, b11{};

#define VM4 asm volatile("s_waitcnt vmcnt(4)" ::: "memory")
#define VM0 asm volatile("s_waitcnt vmcnt(0)" ::: "memory")
#define LGKM0 asm volatile("s_waitcnt lgkmcnt(0)" ::: "memory")
#define NOPV ((void)0)

#define PHASE(CB, KH, MH, DOB, STG, VM) do { \
  const char* const Aq = (CB) + ((KH) << 15); \
  const char* const Bq = Aq + 16384; \
  if (DOB) { \
    b00 = *(const s16x8*)(Bq + boff + 0 * 2048 + sA0); \
    b01 = *(const s16x8*)(Bq + boff + 1 * 2048 + sA0); \
    b10 = *(const s16x8*)(Bq + boff + 0 * 2048 + sA1); \
    b11 = *(const s16x8*)(Bq + boff + 1 * 2048 + sA1); \
  } \
  const s16x8 a0 = *(const s16x8*)(Aq + aoff + (2 * (MH)) * 2048 + sA0); \
  const s16x8 a1 = *(const s16x8*)(Aq + aoff + (2 * (MH)) * 2048 + sA1); \
  const s16x8 a2 = *(const s16x8*)(Aq + aoff + (2 * (MH) + 1) * 2048 + sA0); \
  const s16x8 a3 = *(const s16x8*)(Aq + aoff + (2 * (MH) + 1) * 2048 + sA1); \
  STG; VM; \
  SCHEDB(); SBAR(); LGKM0; SCHEDB(); \
  SETP(1); \
  acc[2 * (MH)][0]     = MFMA(a0, b00, acc[2 * (MH)][0]); \
  acc[2 * (MH)][1]     = MFMA(a0, b01, acc[2 * (MH)][1]); \
  acc[2 * (MH)][0]     = MFMA(a1, b10, acc[2 * (MH)][0]); \
  acc[2 * (MH)][1]     = MFMA(a1, b11, acc[2 * (MH)][1]); \
  acc[2 * (MH) + 1][0] = MFMA(a2, b00, acc[2 * (MH) + 1][0]); \
  acc[2 * (MH) + 1][1] = MFMA(a2, b01, acc[2 * (MH) + 1][1]); \
  acc[2 * (MH) + 1][0] = MFMA(a3, b10, acc[2 * (MH) + 1][0]); \
  acc[2 * (MH) + 1][1] = MFMA(a3, b11, acc[2 * (MH) + 1][1]); \
  SETP(0); \
} while (0)

  stageQ(0, 0); stageQ(0, 1); stageQ(0, 2); stageQ(0, 3);
  VM4; SCHEDB(); SBAR();

  for (int kt = 0; kt < NT - 1; ++kt) {
    const char* const cb = lds + ((kt & 1) << 16);
    PHASE(cb, 0, 0, true,  (stageQ(kt + 1, 0), stageQ(kt + 1, 1)), NOPV);
    PHASE(cb, 0, 1, false, NOPV, VM4);
    PHASE(cb, 1, 0, true,  (stageQ(kt + 1, 2), stageQ(kt + 1, 3)), NOPV);
    PHASE(cb, 1, 1, false, NOPV, VM4);
  }
  {
    const char* const cb = lds + (((NT - 1) & 1) << 16);
    PHASE(cb, 0, 0, true,  NOPV, NOPV);
    PHASE(cb, 0, 1, false, NOPV, VM0);
    PHASE(cb, 1, 0, true,  NOPV, NOPV);
    PHASE(cb, 1, 1, false, NOPV, NOPV);
  }

#undef PHASE
#undef VM4
#undef VM0
#undef LGKM0
#undef NOPV

#pragma unroll
  for (int mf = 0; mf < 4; ++mf) {
#pragma unroll
    for (int nf = 0; nf < 2; ++nf) {
      const int col = (n_t << 8) + (wn << 6) + (nf << 5) + l31;
      const float bv = bx[e * DD + col];
#pragma unroll
      for (int rg = 0; rg < 16; ++rg) {
        const int grow = rowbase + (wm << 7) + (mf << 5) +
                         (rg & 3) + ((rg >> 2) << 3) + (half << 2);
        op[(size_t)grow * DD + col] = acc[mf][nf][rg] + bv;
      }
    }
  }
}

// ===========================================================================
// FALLBACK (round-1 reg-staged path, used only if ws is too small)
// ===========================================================================
__global__ __launch_bounds__(256, 2) void k1_up_swiglu(
    const float* __restrict__ x,  const float* __restrict__ w1,
    const float* __restrict__ b1, const float* __restrict__ w3,
    const float* __restrict__ b3, u16* __restrict__ hbuf) {
  __shared__ __align__(16) char lds[32768];
  char* const As  = lds;
  char* const B1s = lds + 16384;
  char* const B3s = lds + 24576;
  const int bid = blockIdx.x;
  const int e = bid >> 8, rr = bid & 255;
  const int m_t = rr & 15, n_t = rr >> 4;
  const int rowbase = e * TPE + (m_t << 7), colbase = n_t << 6;
  const int t = threadIdx.x, wv = t >> 6, lane = t & 63;
  const int l31 = lane & 31, half = lane >> 5;
  const int wm = wv >> 1, wn = wv & 1;
  const int ag = t & 15, am0 = t >> 4, bn = t & 63, bk0 = t >> 6;
  const float* const xb = x + (size_t)rowbase * DD + (ag << 2);
  const size_t woff = (size_t)e * (DD * HH) + colbase + bn;
  const float* const w1b = w1 + woff;
  const float* const w3b = w3 + woff;
  float4 ra[8]; float rb1[16], rb3[16];
  auto gload = [&](int kt) {
    const float* xp = xb + (kt << 6);
#pragma unroll
    for (int j = 0; j < 8; ++j)
      ra[j] = *(const float4*)(xp + (size_t)(am0 + (j << 4)) * DD);
#pragma unroll
    for (int j = 0; j < 2; ++j) {
      const int k0 = (kt << 6) + ((bk0 + (j << 2)) << 3);
#pragma unroll
      for (int i = 0; i < 8; ++i) {
        rb1[(j << 3) + i] = w1b[(size_t)(k0 + i) * HH];
        rb3[(j << 3) + i] = w3b[(size_t)(k0 + i) * HH];
      }
    }
  };
  f32x16 acc10 = {}, acc11 = {}, acc30 = {}, acc31 = {};
  gload(0);
  for (int kt = 0; kt < 8; ++kt) {
    if (kt) __syncthreads();
#pragma unroll
    for (int j = 0; j < 8; ++j) {
      const int m = am0 + (j << 4);
      uint2 v; v.x = pk2(ra[j].x, ra[j].y); v.y = pk2(ra[j].z, ra[j].w);
      *(uint2*)(As + swz(m, ag << 3)) = v;
    }
#pragma unroll
    for (int j = 0; j < 2; ++j) {
      const int kg = bk0 + (j << 2);
      uint4 v;
      v.x = pk2(rb1[(j << 3) + 0], rb1[(j << 3) + 1]);
      v.y = pk2(rb1[(j << 3) + 2], rb1[(j << 3) + 3]);
      v.z = pk2(rb1[(j << 3) + 4], rb1[(j << 3) + 5]);
      v.w = pk2(rb1[(j << 3) + 6], rb1[(j << 3) + 7]);
      *(uint4*)(B1s + swz(bn, kg << 4)) = v;
      v.x = pk2(rb3[(j << 3) + 0], rb3[(j << 3) + 1]);
      v.y = pk2(rb3[(j << 3) + 2], rb3[(j << 3) + 3]);
      v.z = pk2(rb3[(j << 3) + 4], rb3[(j << 3) + 5]);
      v.w = pk2(rb3[(j << 3) + 6], rb3[(j << 3) + 7]);
      *(uint4*)(B3s + swz(bn, kg << 4)) = v;
    }
    __syncthreads();
    if (kt < 7) gload(kt + 1);
#pragma unroll
    for (int kk = 0; kk < 4; ++kk) {
      const int colb = (kk << 5) + (half << 4);
      const s16x8 a0 = *(const s16x8*)(As  + swz((wm << 6) + l31,      colb));
      const s16x8 a1 = *(const s16x8*)(As  + swz((wm << 6) + 32 + l31, colb));
      const s16x8 f1 = *(const s16x8*)(B1s + swz((wn << 5) + l31,      colb));
      const s16x8 f3 = *(const s16x8*)(B3s + swz((wn << 5) + l31,      colb));
      acc10 = MFMA(a0, f1, acc10); acc30 = MFMA(a0, f3, acc30);
      acc11 = MFMA(a1, f1, acc11); acc31 = MFMA(a1, f3, acc31);
    }
  }
  const int gcol = colbase + (wn << 5) + l31;
  const float bv1 = b1[e * HH + gcol], bv3 = b3[e * HH + gcol];
  u16* const hp = hbuf + gcol;
#pragma unroll
  for (int mb = 0; mb < 2; ++mb) {
    const f32x16 A1 = mb ? acc11 : acc10;
    const f32x16 A3 = mb ? acc31 : acc30;
#pragma unroll
    for (int rg = 0; rg < 16; ++rg) {
      const int grow = rowbase + (wm << 6) + (mb << 5) +
                       (rg & 3) + ((rg >> 2) << 3) + (half << 2);
      const float s1 = A1[rg] + bv1, s3 = A3[rg] + bv3;
      hp[(size_t)grow * HH] = f2bf(s1 * s3 / (1.0f + __expf(-s1)));
    }
  }
}

__global__ __launch_bounds__(256, 2) void k2_down(
    const u16* __restrict__ hbuf, const float* __restrict__ w2,
    const float* __restrict__ b2, float* __restrict__ out) {
  __shared__ __align__(16) char lds[32768];
  char* const As = lds;
  char* const Bs = lds + 16384;
  const int bid = blockIdx.x;
  const int e = bid >> 6, rr = bid & 63;
  const int m_t = rr & 15, n_t = rr >> 4;
  const int rowbase = e * TPE + (m_t << 7), colbase = n_t << 7;
  const int t = threadIdx.x, wv = t >> 6, lane = t & 63;
  const int l31 = lane & 31, half = lane >> 5;
  const int wm = wv >> 1, wn = wv & 1;
  const int ag = t & 7, am0 = t >> 3, bnn = t & 127, bk0 = t >> 7;
  const u16* const hb = hbuf + (size_t)rowbase * HH + (ag << 3);
  const float* const w2b = w2 + (size_t)e * (HH * DD) + colbase + bnn;
  uint4 ra[4]; float rb[32];
  auto gload = [&](int kt) {
#pragma unroll
    for (int j = 0; j < 4; ++j)
      ra[j] = *(const uint4*)(hb + (size_t)(am0 + (j << 5)) * HH + (kt << 6));
#pragma unroll
    for (int j = 0; j < 4; ++j) {
      const int k0 = (kt << 6) + ((bk0 + (j << 1)) << 3);
#pragma unroll
      for (int i = 0; i < 8; ++i)
        rb[(j << 3) + i] = w2b[(size_t)(k0 + i) * DD];
    }
  };
  f32x16 c00 = {}, c01 = {}, c10 = {}, c11 = {};
  gload(0);
  for (int kt = 0; kt < 16; ++kt) {
    if (kt) __syncthreads();
#pragma unroll
    for (int j = 0; j < 4; ++j)
      *(uint4*)(As + swz(am0 + (j << 5), ag << 4)) = ra[j];
#pragma unroll
    for (int j = 0; j < 4; ++j) {
      const int kg = bk0 + (j << 1);
      uint4 v;
      v.x = pk2(rb[(j << 3) + 0], rb[(j << 3) + 1]);
      v.y = pk2(rb[(j << 3) + 2], rb[(j << 3) + 3]);
      v.z = pk2(rb[(j << 3) + 4], rb[(j << 3) + 5]);
      v.w = pk2(rb[(j << 3) + 6], rb[(j << 3) + 7]);
      *(uint4*)(Bs + swz(bnn, kg << 4)) = v;
    }
    __syncthreads();
    if (kt < 15) gload(kt + 1);
#pragma unroll
    for (int kk = 0; kk < 4; ++kk) {
      const int colb = (kk << 5) + (half << 4);
      const s16x8 af0 = *(const s16x8*)(As + swz((wm << 6) + l31,      colb));
      const s16x8 af1 = *(const s16x8*)(As + swz((wm << 6) + 32 + l31, colb));
      const s16x8 bf0 = *(const s16x8*)(Bs + swz((wn << 6) + l31,      colb));
      const s16x8 bf1 = *(const s16x8*)(Bs + swz((wn << 6) + 32 + l31, colb));
      c00 = MFMA(af0, bf0, c00); c01 = MFMA(af0, bf1, c01);
      c10 = MFMA(af1, bf0, c10); c11 = MFMA(af1, bf1, c11);
    }
  }
#pragma unroll
  for (int mb = 0; mb < 2; ++mb) {
#pragma unroll
    for (int nb = 0; nb < 2; ++nb) {
      const f32x16 c = mb ? (nb ? c11 : c10) : (nb ? c01 : c00);
      const int gcol = colbase + (wn << 6) + (nb << 5) + l31;
      const float bv = b2[e * DD + gcol];
#pragma unroll
      for (int rg = 0; rg < 16; ++rg) {
        const int grow = rowbase + (wm << 6) + (mb << 5) +
                         (rg & 3) + ((rg >> 2) << 3) + (half << 2);
        out[(size_t)grow * DD + gcol] = c[rg] + bv;
      }
    }
  }
}

// ---------------------------------------------------------------------------
extern "C" void kernel_launch(void* const* d_in, const int* in_sizes, int n_in,
                              void* d_out, int out_size, void* d_ws, size_t ws_size,
                              hipStream_t stream) {
  const float* x  = (const float*)d_in[0];
  const float* w1 = (const float*)d_in[1];
  const float* b1 = (const float*)d_in[2];
  const float* w3 = (const float*)d_in[3];
  const float* b3 = (const float*)d_in[4];
  const float* w2 = (const float*)d_in[5];
  const float* b2 = (const float*)d_in[6];

  const size_t W13T_B = (size_t)NE * 2 * HH * DD * 2;  //  64 MiB
  const size_t W2T_B  = (size_t)NE * DD * HH * 2;      //  32 MiB
  const size_t H_B    = (size_t)TOK * HH * 2;          // 128 MiB

  if (ws_size >= W13T_B + W2T_B + H_B) {
    u16* const xb   = (u16*)d_out;                     // dead until g1 epilogue
    u16* const w13t = (u16*)d_ws;
    u16* const w2t  = (u16*)((char*)d_ws + W13T_B);
    u16* const hbuf = (u16*)((char*)d_ws + W13T_B + W2T_B);

    p123   <<<dim3(16384 + NE * 256), dim3(256), 0, stream>>>(
        x, w1, w3, w2, xb, w13t, w2t);
    g0_pers<<<dim3(256), dim3(512), 0, stream>>>(xb, w13t, b1, b3, hbuf);
    g1_down<<<dim3(NE * 16), dim3(512), 0, stream>>>(hbuf, w2t, b2, (float*)d_out);
  } else {
    u16* hbuf = (ws_size >= H_B) ? (u16*)d_ws : (u16*)d_out;
    k1_up_swiglu<<<dim3(NE * 256), dim3(256), 0, stream>>>(x, w1, b1, w3, b3, hbuf);
    k2_down<<<dim3(NE * 64), dim3(256), 0, stream>>>(hbuf, w2, b2, (float*)d_out);
  }
}

// Round 10
// 344.871 us; speedup vs baseline: 1.1237x; 1.0464x over previous
//
#include <hip/hip_runtime.h>
#include <hip/hip_bf16.h>

#define TOK 65536
#define NE  32
#define DD  512
#define HH  1024
#define TPE 2048   // tokens per expert (uniform dispatch)

typedef short s16x8  __attribute__((ext_vector_type(8)));
typedef float f32x16 __attribute__((ext_vector_type(16)));
using u16 = unsigned short;
using u32 = unsigned int;

__device__ __forceinline__ u16 f2bf(float f) {
  __bf16 h = (__bf16)f;
  return __builtin_bit_cast(u16, h);
}
__device__ __forceinline__ u32 pk2(float lo, float hi) {
  return (u32)f2bf(lo) | ((u32)f2bf(hi) << 16);
}
__device__ __forceinline__ int swz(int row, int colb) {
  return (row << 7) + (colb ^ ((row & 7) << 4));
}

#define MFMA(a, b, c) __builtin_amdgcn_mfma_f32_32x32x16_bf16(a, b, c, 0, 0, 0)
#define GLD(src, dst) __builtin_amdgcn_global_load_lds( \
    (const __attribute__((address_space(1))) void*)(src), \
    (__attribute__((address_space(3))) void*)(dst), 16, 0, 0)
#define SETP(n) __builtin_amdgcn_s_setprio(n)
#define SCHEDB() __builtin_amdgcn_sched_barrier(0)
#define SBAR()  __builtin_amdgcn_s_barrier()

// ===========================================================================
// Merged prepass (r9-proven): blocks [0,16384) x->xb bf16;
// [16384,20480) w1,w3 -> w13t (bf16 [E][2H][D], 64-row interleave so SwiGLU
// pairs land in one wave); [20480,24576) w2 -> w2t (bf16 [E][D][H]).
// ===========================================================================
__global__ __launch_bounds__(256) void p123(
    const float* __restrict__ x,  const float* __restrict__ w1,
    const float* __restrict__ w3, const float* __restrict__ w2,
    u16* __restrict__ xb, u16* __restrict__ w13t, u16* __restrict__ w2t) {
  __shared__ __align__(16) u16 L1[64 * 72], L3[64 * 72];
  const int bid0 = blockIdx.x;
  const int t = threadIdx.x;

  if (bid0 < 16384) {                 // ---- x -> xb ----
    const size_t i = ((size_t)bid0 * 256 + t) * 8;
    const float4 a = *(const float4*)(x + i);
    const float4 b = *(const float4*)(x + i + 4);
    uint4 v;
    v.x = pk2(a.x, a.y); v.y = pk2(a.z, a.w);
    v.z = pk2(b.x, b.y); v.w = pk2(b.z, b.w);
    *(uint4*)(xb + i) = v;
    return;
  }
  const int cg = (t & 15) << 2, rbase = t >> 4;
  const int cb8 = (t & 7) << 3;
  if (bid0 < 16384 + NE * 128) {      // ---- w1,w3 -> w13t ----
    const int bid = bid0 - 16384;
    const int e = bid >> 7, rr = bid & 127;
    const int d0 = (rr & 7) << 6, h0 = (rr >> 3) << 6;
    const float* const s1 = w1 + (size_t)e * DD * HH + (size_t)d0 * HH + h0;
    const float* const s3 = w3 + (size_t)e * DD * HH + (size_t)d0 * HH + h0;
#pragma unroll
    for (int j = 0; j < 4; ++j) {
      const int dr = rbase + (j << 4);
      const float4 a = *(const float4*)(s1 + (size_t)dr * HH + cg);
      const float4 b = *(const float4*)(s3 + (size_t)dr * HH + cg);
      L1[(cg + 0) * 72 + dr] = f2bf(a.x); L1[(cg + 1) * 72 + dr] = f2bf(a.y);
      L1[(cg + 2) * 72 + dr] = f2bf(a.z); L1[(cg + 3) * 72 + dr] = f2bf(a.w);
      L3[(cg + 0) * 72 + dr] = f2bf(b.x); L3[(cg + 1) * 72 + dr] = f2bf(b.y);
      L3[(cg + 2) * 72 + dr] = f2bf(b.z); L3[(cg + 3) * 72 + dr] = f2bf(b.w);
    }
    __syncthreads();
    u16* const dst = w13t + (size_t)e * (2 * HH) * DD;
#pragma unroll
    for (int j = 0; j < 2; ++j) {
      const int nloc = (t >> 3) + (j << 5);
      const int n = h0 + nloc;
      const int R1 = ((n >> 5) << 6) + (n & 31);
      const uint4 v1 = *(const uint4*)(L1 + nloc * 72 + cb8);
      const uint4 v3 = *(const uint4*)(L3 + nloc * 72 + cb8);
      *(uint4*)(dst + (size_t)R1 * DD + d0 + cb8) = v1;
      *(uint4*)(dst + (size_t)(R1 + 32) * DD + d0 + cb8) = v3;
    }
  } else {                            // ---- w2 -> w2t ----
    const int bid = bid0 - 16384 - NE * 128;
    const int e = bid >> 7, rr = bid & 127;
    const int d0 = (rr & 7) << 6, h0 = (rr >> 3) << 6;
    const float* const s = w2 + (size_t)e * HH * DD + (size_t)h0 * DD + d0;
#pragma unroll
    for (int j = 0; j < 4; ++j) {
      const int hr = rbase + (j << 4);
      const float4 a = *(const float4*)(s + (size_t)hr * DD + cg);
      L1[(cg + 0) * 72 + hr] = f2bf(a.x); L1[(cg + 1) * 72 + hr] = f2bf(a.y);
      L1[(cg + 2) * 72 + hr] = f2bf(a.z); L1[(cg + 3) * 72 + hr] = f2bf(a.w);
    }
    __syncthreads();
    u16* const dst = w2t + (size_t)e * DD * HH;
#pragma unroll
    for (int j = 0; j < 2; ++j) {
      const int dloc = (t >> 3) + (j << 5);
      const uint4 v = *(const uint4*)(L1 + dloc * 72 + cb8);
      *(uint4*)(dst + (size_t)(d0 + dloc) * HH + h0 + cb8) = v;
    }
  }
}

// ===========================================================================
// g0: r7-proven 128x128 GEMM (GLD both operands, 3 blocks/CU, XCD chunk
// swizzle -> FETCH 71 MB). A=xb bf16 [T,512], B=w13t panels.
// h = swiglu(x@w13 + b) -> bf16.
// ===========================================================================
__global__ __launch_bounds__(256, 3) void g0_up(
    const u16* __restrict__ A, const u16* __restrict__ Bm,
    const float* __restrict__ bx, const float* __restrict__ by,
    u16* __restrict__ hp) {
  constexpr int K = DD;           // 512
  __shared__ __align__(16) char lds[32768];
  char* const As = lds;
  char* const Bs = lds + 16384;

  int bid = blockIdx.x;
  bid = (bid & 7) * (NE * 256 / 8) + (bid >> 3);   // bijective XCD chunk
  const int e   = bid >> 8;
  const int rr  = bid & 255;
  const int m_t = rr & 15;        // m fastest -> consecutive blocks share B
  const int n_t = rr >> 4;
  const int rowbase = e * TPE + (m_t << 7);

  const int t = threadIdx.x, wv = t >> 6, lane = t & 63;
  const int l31 = lane & 31, half = lane >> 5;
  const int wm = wv >> 1, wn = wv & 1;

  const u16* const Abase = A + (size_t)rowbase * K;
  const u16* const Bbase = Bm + ((size_t)e * 2048 + (size_t)n_t * 128) * K;

  int soff[4], lb[4];
#pragma unroll
  for (int j = 0; j < 4; ++j) {
    const int idx = (j << 8) + t;          // 16-B chunk index in [0,1024)
    const int r = idx >> 3;                // tile row 0..127
    const int cb = ((idx & 7) << 4) ^ ((r & 7) << 4);  // pre-swizzled src byte
    soff[j] = r * K + (cb >> 1);
    lb[j] = ((j << 8) + (wv << 6)) << 4;   // wave-uniform LDS byte base
  }

  f32x16 c00 = {}, c01 = {}, c10 = {}, c11 = {};
  const int sw  = (l31 & 7) << 4;
  const int ra0 = ((wm << 6) + l31) << 7, ra1 = ra0 + (32 << 7);
  const int rb0 = ((wn << 6) + l31) << 7, rb1 = rb0 + (32 << 7);

  for (int kt = 0; kt < 8; ++kt) {
    const u16* const Ak = Abase + (kt << 6);
    const u16* const Bk = Bbase + (kt << 6);
#pragma unroll
    for (int j = 0; j < 4; ++j) {
      GLD(Ak + soff[j], As + lb[j]);
      GLD(Bk + soff[j], Bs + lb[j]);
    }
    __syncthreads();                 // drains vmcnt -> LDS tiles ready
#pragma unroll
    for (int ks = 0; ks < 4; ++ks) {
      const int ko = ((ks << 5) + (half << 4)) ^ sw;
      const s16x8 a0 = *(const s16x8*)(As + ra0 + ko);
      const s16x8 a1 = *(const s16x8*)(As + ra1 + ko);
      const s16x8 b0 = *(const s16x8*)(Bs + rb0 + ko);
      const s16x8 b1 = *(const s16x8*)(Bs + rb1 + ko);
      c00 = MFMA(a0, b0, c00); c01 = MFMA(a0, b1, c01);
      c10 = MFMA(a1, b0, c10); c11 = MFMA(a1, b1, c11);
    }
    __syncthreads();                 // protect LDS before next stage
  }

  const int hcol = (n_t << 6) + (wn << 5) + l31;
  const float bv1 = bx[e * HH + hcol];
  const float bv3 = by[e * HH + hcol];
#pragma unroll
  for (int mf = 0; mf < 2; ++mf) {
    const f32x16 A1 = mf ? c10 : c00;
    const f32x16 A3 = mf ? c11 : c01;
#pragma unroll
    for (int rg = 0; rg < 16; ++rg) {
      // C/D map: col=lane&31, row=(rg&3)+8*(rg>>2)+4*(lane>>5)
      const int grow = rowbase + (wm << 6) + (mf << 5) +
                       (rg & 3) + ((rg >> 2) << 3) + (half << 2);
      const float s1 = A1[rg] + bv1;
      const float s3 = A3[rg] + bv3;
      hp[(size_t)grow * HH + hcol] = f2bf(s1 * s3 / (1.0f + __expf(-s1)));
    }
  }
}

// ===========================================================================
// g1: r5/r7-proven 256x256 4-phase pipelined GEMM (reads-pre-barrier), K=1024.
// A=h bf16 [T,1024], B=w2t panels, epilogue +b2 -> out fp32.
// ===========================================================================
__global__ __launch_bounds__(512, 2) void g1_down(
    const u16* __restrict__ A, const u16* __restrict__ Bm,
    const float* __restrict__ bx, float* __restrict__ op) {
  constexpr int K  = HH;                // 1024
  constexpr int NT = K >> 6;            // 16
  constexpr int NB = 2;                 // 256-wide n-tiles per expert
  constexpr int NWG = NE * 8 * NB;      // 512
  __shared__ __align__(16) char lds[131072];

  int bid = blockIdx.x;
  bid = (bid & 7) * (NWG / 8) + (bid >> 3);
  const int e   = bid / (8 * NB);
  const int rr  = bid % (8 * NB);
  const int m_t = rr & 7;
  const int n_t = rr >> 3;
  const int rowbase = e * TPE + (m_t << 8);

  const int t = threadIdx.x;
  const int wv = t >> 6, lane = t & 63;
  const int l31 = lane & 31, half = lane >> 5;
  const int wm = wv >> 2, wn = wv & 3;  // 2 x 4 waves; wave owns 128x64

  const u16* const Abase = A + (size_t)rowbase * K;
  const u16* const Bbase = Bm + ((size_t)e * NB + n_t) * 256 * K;

  int srcoff0, srcoff1;
  {
    const int c0 = t,       lr0 = c0 >> 3, s0 = (c0 & 7) ^ (lr0 & 7);
    const int c1 = 512 + t, lr1 = c1 >> 3, s1 = (c1 & 7) ^ (lr1 & 7);
    srcoff0 = ((lr0 << 1) | (s0 >> 2)) * K + ((s0 & 3) << 3);
    srcoff1 = ((lr1 << 1) | (s1 >> 2)) * K + ((s1 & 3) << 3);
  }
  const int t16 = t << 4;

  auto stageQ = [&](int tau, int q) {   // q: 0=Ak0 1=Bk0 2=Ak1 3=Bk1
    const u16* const src = ((q & 1) ? Bbase : Abase) + tau * 64 + (q >> 1) * 32;
    char* const dst = lds + ((tau & 1) << 16) + (q << 14);
    GLD(src + srcoff0, dst + t16);
    GLD(src + srcoff1, dst + 8192 + t16);
  };

  const int lrow_off = l31 >> 1;
  const int pbit = l31 & 1;
  const int sw7 = lrow_off & 7;
  const int sA0 = (((pbit << 2) | 0 | half) ^ sw7) << 4;  // ksp=0
  const int sA1 = (((pbit << 2) | 2 | half) ^ sw7) << 4;  // ksp=1
  const int aoff = ((wm << 6) + lrow_off) << 7;
  const int boff = ((wn << 5) + lrow_off) << 7;

  f32x16 acc[4][2] = {};
  s16x8 b00{}, b01{}, b10{}, b11{};

#define VM4 asm volatile("s_waitcnt vmcnt(4)" ::: "memory")
#define VM0 asm volatile("s_waitcnt vmcnt(0)" ::: "memory")
#define LGKM0 asm volatile("s_waitcnt lgkmcnt(0)" ::: "memory")
#define NOPV ((void)0)

#define PHASE(CB, KH, MH, DOB, STG, VM) do { \
  const char* const Aq = (CB) + ((KH) << 15); \
  const char* const Bq = Aq + 16384; \
  if (DOB) { \
    b00 = *(const s16x8*)(Bq + boff + 0 * 2048 + sA0); \
    b01 = *(const s16x8*)(Bq + boff + 1 * 2048 + sA0); \
    b10 = *(const s16x8*)(Bq + boff + 0 * 2048 + sA1); \
    b11 = *(const s16x8*)(Bq + boff + 1 * 2048 + sA1); \
  } \
  const s16x8 a0 = *(const s16x8*)(Aq + aoff + (2 * (MH)) * 2048 + sA0); \
  const s16x8 a1 = *(const s16x8*)(Aq + aoff + (2 * (MH)) * 2048 + sA1); \
  const s16x8 a2 = *(const s16x8*)(Aq + aoff + (2 * (MH) + 1) * 2048 + sA0); \
  const s16x8 a3 = *(const s16x8*)(Aq + aoff + (2 * (MH) + 1) * 2048 + sA1); \
  STG; VM; \
  SCHEDB(); SBAR(); LGKM0; SCHEDB(); \
  SETP(1); \
  acc[2 * (MH)][0]     = MFMA(a0, b00, acc[2 * (MH)][0]); \
  acc[2 * (MH)][1]     = MFMA(a0, b01, acc[2 * (MH)][1]); \
  acc[2 * (MH)][0]     = MFMA(a1, b10, acc[2 * (MH)][0]); \
  acc[2 * (MH)][1]     = MFMA(a1, b11, acc[2 * (MH)][1]); \
  acc[2 * (MH) + 1][0] = MFMA(a2, b00, acc[2 * (MH) + 1][0]); \
  acc[2 * (MH) + 1][1] = MFMA(a2, b01, acc[2 * (MH) + 1][1]); \
  acc[2 * (MH) + 1][0] = MFMA(a3, b10, acc[2 * (MH) + 1][0]); \
  acc[2 * (MH) + 1][1] = MFMA(a3, b11, acc[2 * (MH) + 1][1]); \
  SETP(0); \
} while (0)

  stageQ(0, 0); stageQ(0, 1); stageQ(0, 2); stageQ(0, 3);
  VM4; SCHEDB(); SBAR();

  for (int kt = 0; kt < NT - 1; ++kt) {
    const char* const cb = lds + ((kt & 1) << 16);
    PHASE(cb, 0, 0, true,  (stageQ(kt + 1, 0), stageQ(kt + 1, 1)), NOPV);
    PHASE(cb, 0, 1, false, NOPV, VM4);
    PHASE(cb, 1, 0, true,  (stageQ(kt + 1, 2), stageQ(kt + 1, 3)), NOPV);
    PHASE(cb, 1, 1, false, NOPV, VM4);
  }
  {
    const char* const cb = lds + (((NT - 1) & 1) << 16);
    PHASE(cb, 0, 0, true,  NOPV, NOPV);
    PHASE(cb, 0, 1, false, NOPV, VM0);
    PHASE(cb, 1, 0, true,  NOPV, NOPV);
    PHASE(cb, 1, 1, false, NOPV, NOPV);
  }

#undef PHASE
#undef VM4
#undef VM0
#undef LGKM0
#undef NOPV

#pragma unroll
  for (int mf = 0; mf < 4; ++mf) {
#pragma unroll
    for (int nf = 0; nf < 2; ++nf) {
      const int col = (n_t << 8) + (wn << 6) + (nf << 5) + l31;
      const float bv = bx[e * DD + col];
#pragma unroll
      for (int rg = 0; rg < 16; ++rg) {
        const int grow = rowbase + (wm << 7) + (mf << 5) +
                         (rg & 3) + ((rg >> 2) << 3) + (half << 2);
        op[(size_t)grow * DD + col] = acc[mf][nf][rg] + bv;
      }
    }
  }
}

// ===========================================================================
// FALLBACK (round-1 reg-staged path, used only if ws is too small)
// ===========================================================================
__global__ __launch_bounds__(256, 2) void k1_up_swiglu(
    const float* __restrict__ x,  const float* __restrict__ w1,
    const float* __restrict__ b1, const float* __restrict__ w3,
    const float* __restrict__ b3, u16* __restrict__ hbuf) {
  __shared__ __align__(16) char lds[32768];
  char* const As  = lds;
  char* const B1s = lds + 16384;
  char* const B3s = lds + 24576;
  const int bid = blockIdx.x;
  const int e = bid >> 8, rr = bid & 255;
  const int m_t = rr & 15, n_t = rr >> 4;
  const int rowbase = e * TPE + (m_t << 7), colbase = n_t << 6;
  const int t = threadIdx.x, wv = t >> 6, lane = t & 63;
  const int l31 = lane & 31, half = lane >> 5;
  const int wm = wv >> 1, wn = wv & 1;
  const int ag = t & 15, am0 = t >> 4, bn = t & 63, bk0 = t >> 6;
  const float* const xb = x + (size_t)rowbase * DD + (ag << 2);
  const size_t woff = (size_t)e * (DD * HH) + colbase + bn;
  const float* const w1b = w1 + woff;
  const float* const w3b = w3 + woff;
  float4 ra[8]; float rb1[16], rb3[16];
  auto gload = [&](int kt) {
    const float* xp = xb + (kt << 6);
#pragma unroll
    for (int j = 0; j < 8; ++j)
      ra[j] = *(const float4*)(xp + (size_t)(am0 + (j << 4)) * DD);
#pragma unroll
    for (int j = 0; j < 2; ++j) {
      const int k0 = (kt << 6) + ((bk0 + (j << 2)) << 3);
#pragma unroll
      for (int i = 0; i < 8; ++i) {
        rb1[(j << 3) + i] = w1b[(size_t)(k0 + i) * HH];
        rb3[(j << 3) + i] = w3b[(size_t)(k0 + i) * HH];
      }
    }
  };
  f32x16 acc10 = {}, acc11 = {}, acc30 = {}, acc31 = {};
  gload(0);
  for (int kt = 0; kt < 8; ++kt) {
    if (kt) __syncthreads();
#pragma unroll
    for (int j = 0; j < 8; ++j) {
      const int m = am0 + (j << 4);
      uint2 v; v.x = pk2(ra[j].x, ra[j].y); v.y = pk2(ra[j].z, ra[j].w);
      *(uint2*)(As + swz(m, ag << 3)) = v;
    }
#pragma unroll
    for (int j = 0; j < 2; ++j) {
      const int kg = bk0 + (j << 2);
      uint4 v;
      v.x = pk2(rb1[(j << 3) + 0], rb1[(j << 3) + 1]);
      v.y = pk2(rb1[(j << 3) + 2], rb1[(j << 3) + 3]);
      v.z = pk2(rb1[(j << 3) + 4], rb1[(j << 3) + 5]);
      v.w = pk2(rb1[(j << 3) + 6], rb1[(j << 3) + 7]);
      *(uint4*)(B1s + swz(bn, kg << 4)) = v;
      v.x = pk2(rb3[(j << 3) + 0], rb3[(j << 3) + 1]);
      v.y = pk2(rb3[(j << 3) + 2], rb3[(j << 3) + 3]);
      v.z = pk2(rb3[(j << 3) + 4], rb3[(j << 3) + 5]);
      v.w = pk2(rb3[(j << 3) + 6], rb3[(j << 3) + 7]);
      *(uint4*)(B3s + swz(bn, kg << 4)) = v;
    }
    __syncthreads();
    if (kt < 7) gload(kt + 1);
#pragma unroll
    for (int kk = 0; kk < 4; ++kk) {
      const int colb = (kk << 5) + (half << 4);
      const s16x8 a0 = *(const s16x8*)(As  + swz((wm << 6) + l31,      colb));
      const s16x8 a1 = *(const s16x8*)(As  + swz((wm << 6) + 32 + l31, colb));
      const s16x8 f1 = *(const s16x8*)(B1s + swz((wn << 5) + l31,      colb));
      const s16x8 f3 = *(const s16x8*)(B3s + swz((wn << 5) + l31,      colb));
      acc10 = MFMA(a0, f1, acc10); acc30 = MFMA(a0, f3, acc30);
      acc11 = MFMA(a1, f1, acc11); acc31 = MFMA(a1, f3, acc31);
    }
  }
  const int gcol = colbase + (wn << 5) + l31;
  const float bv1 = b1[e * HH + gcol], bv3 = b3[e * HH + gcol];
  u16* const hp = hbuf + gcol;
#pragma unroll
  for (int mb = 0; mb < 2; ++mb) {
    const f32x16 A1 = mb ? acc11 : acc10;
    const f32x16 A3 = mb ? acc31 : acc30;
#pragma unroll
    for (int rg = 0; rg < 16; ++rg) {
      const int grow = rowbase + (wm << 6) + (mb << 5) +
                       (rg & 3) + ((rg >> 2) << 3) + (half << 2);
      const float s1 = A1[rg] + bv1, s3 = A3[rg] + bv3;
      hp[(size_t)grow * HH] = f2bf(s1 * s3 / (1.0f + __expf(-s1)));
    }
  }
}

__global__ __launch_bounds__(256, 2) void k2_down(
    const u16* __restrict__ hbuf, const float* __restrict__ w2,
    const float* __restrict__ b2, float* __restrict__ out) {
  __shared__ __align__(16) char lds[32768];
  char* const As = lds;
  char* const Bs = lds + 16384;
  const int bid = blockIdx.x;
  const int e = bid >> 6, rr = bid & 63;
  const int m_t = rr & 15, n_t = rr >> 4;
  const int rowbase = e * TPE + (m_t << 7), colbase = n_t << 7;
  const int t = threadIdx.x, wv = t >> 6, lane = t & 63;
  const int l31 = lane & 31, half = lane >> 5;
  const int wm = wv >> 1, wn = wv & 1;
  const int ag = t & 7, am0 = t >> 3, bnn = t & 127, bk0 = t >> 7;
  const u16* const hb = hbuf + (size_t)rowbase * HH + (ag << 3);
  const float* const w2b = w2 + (size_t)e * (HH * DD) + colbase + bnn;
  uint4 ra[4]; float rb[32];
  auto gload = [&](int kt) {
#pragma unroll
    for (int j = 0; j < 4; ++j)
      ra[j] = *(const uint4*)(hb + (size_t)(am0 + (j << 5)) * HH + (kt << 6));
#pragma unroll
    for (int j = 0; j < 4; ++j) {
      const int k0 = (kt << 6) + ((bk0 + (j << 1)) << 3);
#pragma unroll
      for (int i = 0; i < 8; ++i)
        rb[(j << 3) + i] = w2b[(size_t)(k0 + i) * DD];
    }
  };
  f32x16 c00 = {}, c01 = {}, c10 = {}, c11 = {};
  gload(0);
  for (int kt = 0; kt < 16; ++kt) {
    if (kt) __syncthreads();
#pragma unroll
    for (int j = 0; j < 4; ++j)
      *(uint4*)(As + swz(am0 + (j << 5), ag << 4)) = ra[j];
#pragma unroll
    for (int j = 0; j < 4; ++j) {
      const int kg = bk0 + (j << 1);
      uint4 v;
      v.x = pk2(rb[(j << 3) + 0], rb[(j << 3) + 1]);
      v.y = pk2(rb[(j << 3) + 2], rb[(j << 3) + 3]);
      v.z = pk2(rb[(j << 3) + 4], rb[(j << 3) + 5]);
      v.w = pk2(rb[(j << 3) + 6], rb[(j << 3) + 7]);
      *(uint4*)(Bs + swz(bnn, kg << 4)) = v;
    }
    __syncthreads();
    if (kt < 15) gload(kt + 1);
#pragma unroll
    for (int kk = 0; kk < 4; ++kk) {
      const int colb = (kk << 5) + (half << 4);
      const s16x8 af0 = *(const s16x8*)(As + swz((wm << 6) + l31,      colb));
      const s16x8 af1 = *(const s16x8*)(As + swz((wm << 6) + 32 + l31, colb));
      const s16x8 bf0 = *(const s16x8*)(Bs + swz((wn << 6) + l31,      colb));
      const s16x8 bf1 = *(const s16x8*)(Bs + swz((wn << 6) + 32 + l31, colb));
      c00 = MFMA(af0, bf0, c00); c01 = MFMA(af0, bf1, c01);
      c10 = MFMA(af1, bf0, c10); c11 = MFMA(af1, bf1, c11);
    }
  }
#pragma unroll
  for (int mb = 0; mb < 2; ++mb) {
#pragma unroll
    for (int nb = 0; nb < 2; ++nb) {
      const f32x16 c = mb ? (nb ? c11 : c10) : (nb ? c01 : c00);
      const int gcol = colbase + (wn << 6) + (nb << 5) + l31;
      const float bv = b2[e * DD + gcol];
#pragma unroll
      for (int rg = 0; rg < 16; ++rg) {
        const int grow = rowbase + (wm << 6) + (mb << 5) +
                         (rg & 3) + ((rg >> 2) << 3) + (half << 2);
        out[(size_t)grow * DD + gcol] = c[rg] + bv;
      }
    }
  }
}

// ---------------------------------------------------------------------------
extern "C" void kernel_launch(void* const* d_in, const int* in_sizes, int n_in,
                              void* d_out, int out_size, void* d_ws, size_t ws_size,
                              hipStream_t stream) {
  const float* x  = (const float*)d_in[0];
  const float* w1 = (const float*)d_in[1];
  const float* b1 = (const float*)d_in[2];
  const float* w3 = (const float*)d_in[3];
  const float* b3 = (const float*)d_in[4];
  const float* w2 = (const float*)d_in[5];
  const float* b2 = (const float*)d_in[6];

  const size_t W13T_B = (size_t)NE * 2 * HH * DD * 2;  //  64 MiB
  const size_t W2T_B  = (size_t)NE * DD * HH * 2;      //  32 MiB
  const size_t H_B    = (size_t)TOK * HH * 2;          // 128 MiB

  if (ws_size >= W13T_B + W2T_B + H_B) {
    u16* const xb   = (u16*)d_out;                     // dead until g1 epilogue
    u16* const w13t = (u16*)d_ws;
    u16* const w2t  = (u16*)((char*)d_ws + W13T_B);
    u16* const hbuf = (u16*)((char*)d_ws + W13T_B + W2T_B);

    p123   <<<dim3(16384 + NE * 256), dim3(256), 0, stream>>>(
        x, w1, w3, w2, xb, w13t, w2t);
    g0_up  <<<dim3(NE * 256), dim3(256), 0, stream>>>(xb, w13t, b1, b3, hbuf);
    g1_down<<<dim3(NE * 16),  dim3(512), 0, stream>>>(hbuf, w2t, b2, (float*)d_out);
  } else {
    u16* hbuf = (ws_size >= H_B) ? (u16*)d_ws : (u16*)d_out;
    k1_up_swiglu<<<dim3(NE * 256), dim3(256), 0, stream>>>(x, w1, b1, w3, b3, hbuf);
    k2_down<<<dim3(NE * 64), dim3(256), 0, stream>>>(hbuf, w2, b2, (float*)d_out);
  }
}